// Round 6
// baseline (706.079 us; speedup 1.0000x reference)
//
#include <hip/hip_runtime.h>
#include <hip/hip_cooperative_groups.h>
#include <stdint.h>

namespace cg = cooperative_groups;

#define DEV_INLINE __device__ __forceinline__

typedef __bf16 bf16x8 __attribute__((ext_vector_type(8)));
typedef float f32x4 __attribute__((ext_vector_type(4)));

typedef const __attribute__((address_space(1))) void* gas_ptr;
typedef __attribute__((address_space(3))) void* las_ptr;

DEV_INLINE unsigned short f2bf(float f) {
    union { __bf16 h; unsigned short u; } v;
    v.h = (__bf16)f;            // native RNE cvt
    return v.u;
}

template <int N> DEV_INLINE void waitcnt_vm() {
    asm volatile("s_waitcnt vmcnt(%0)" :: "n"(N) : "memory");
}
DEV_INLINE void hard_barrier() {
    __builtin_amdgcn_sched_barrier(0);
    __builtin_amdgcn_s_barrier();
    __builtin_amdgcn_sched_barrier(0);
}

// ------- prep: casts + bias + 3 transposes + SIMCAST (one launch) -------
__global__ __launch_bounds__(256)
void prep_all_kernel(const float* __restrict__ x, unsigned short* __restrict__ xb,
                     const float* __restrict__ Wkv, unsigned short* __restrict__ wkvb,
                     const float* __restrict__ bq, const float* __restrict__ bkv,
                     float* __restrict__ bias1, float* __restrict__ zbuf,
                     const float* __restrict__ Wq, const float* __restrict__ Wp,
                     unsigned short* __restrict__ w1t, unsigned short* __restrict__ wpt,
                     const float* __restrict__ sim, unsigned short* __restrict__ simb) {
    __shared__ float tl[64][65];
    const int bid = blockIdx.x, t = threadIdx.x;
    if (bid >= 2124) {
        long i = (long)(bid - 2124) * 256 + t;        // ushort8 index, 3145728 total
        const float4* sp = (const float4*)sim + i * 2;
        float4 a = sp[0], b = sp[1];
        union { bf16x8 v; unsigned short u[8]; } pk;
        pk.u[0] = f2bf(a.x); pk.u[1] = f2bf(a.y);
        pk.u[2] = f2bf(a.z); pk.u[3] = f2bf(a.w);
        pk.u[4] = f2bf(b.x); pk.u[5] = f2bf(b.y);
        pk.u[6] = f2bf(b.z); pk.u[7] = f2bf(b.w);
        ((bf16x8*)simb)[i] = pk.v;
        return;
    }
    if (bid < 1536) {
        const float* s; unsigned short* d; long i;
        if (bid < 384) { s = x;   d = xb;   i = (long)bid * 256 + t; }
        else           { s = Wkv; d = wkvb; i = (long)(bid - 384) * 256 + t; }
        float4 a = ((const float4*)s)[i];
        ushort4 o;
        o.x = f2bf(a.x); o.y = f2bf(a.y); o.z = f2bf(a.z); o.w = f2bf(a.w);
        ((ushort4*)d)[i] = o;
    } else if (bid < 1548) {
        int i = (bid - 1536) * 256 + t;   // [0,3072)
        if (i < 768) bias1[i] = bq[i];
        else if (i < 2304) bias1[i] = bkv[i - 768];
        else zbuf[i - 2304] = 0.f;
    } else {
        int tb = bid - 1548;              // [0,576)
        int bx = tb % 48, by = tb / 48;
        const float* src; unsigned short* dst; int C;
        if (bx < 12)      { src = Wq;  dst = w1t;              C = 768; }
        else if (bx < 36) { src = Wkv; dst = w1t + 768L * 768; C = 1536; bx -= 12; }
        else              { src = Wp;  dst = wpt;              C = 768; bx -= 36; }
        int c0 = bx * 64, r0 = by * 64;
        int tx = t & 63, ty = t >> 6;     // 64 x 4
        #pragma unroll
        for (int i = 0; i < 64; i += 4)
            tl[ty + i][tx] = src[(long)(r0 + ty + i) * C + c0 + tx];
        __syncthreads();
        #pragma unroll
        for (int i = 0; i < 64; i += 4)
            dst[(long)(c0 + ty + i) * 768 + r0 + tx] = f2bf(tl[tx][ty + i]);
    }
}

// ---------------- unified bf16 MFMA GEMM body (2-phase pipelined) ----------------
template <int WM, int WN, int WAVES_M, bool G1E>
DEV_INLINE void gemm_body(const unsigned short* A, int lda,
                          const unsigned short* BT, int ldb,
                          const unsigned short* A2, int lda2,
                          const unsigned short* B2, int ldb2, int K1,
                          const float* bias, void* Cout, int ldc, int K,
                          const float* cin, int OUT, long obase, long tm, long tn,
                          unsigned short* As, unsigned short* Bs,
                          float* g1_qf, unsigned short* g1_qb,
                          unsigned short* g1_kxb, unsigned short* g1_vxT) {
    constexpr int TR = WAVES_M * WM * 16;
    constexpr int TC = (4 / WAVES_M) * WN * 16;
    constexpr int NL = TR / 32 + TC / 32;   // global_load_lds per wave per stage
    const int tid = threadIdx.x;
    const int w = tid >> 6, lane = tid & 63;
    const int lm = lane & 15, quad = lane >> 4;
    const int m_off = (w % WAVES_M) * WM * 16;
    const int n_off = (w / WAVES_M) * WN * 16;
    const int lrow8 = lane >> 3;
    const int lcol_sw = (((lane & 7) ^ lrow8) * 8);

    f32x4 acc[WM][WN];
    #pragma unroll
    for (int mi = 0; mi < WM; ++mi)
        #pragma unroll
        for (int ni = 0; ni < WN; ++ni) acc[mi][ni] = f32x4{0.f, 0.f, 0.f, 0.f};

    auto stage = [&](int k0, int pb) {
        const unsigned short* Ab; const unsigned short* Bb;
        int la, lb, kc;
        if (k0 < K1) { Ab = A;  Bb = BT; la = lda;  lb = ldb;  kc = k0; }
        else         { Ab = A2; Bb = B2; la = lda2; lb = ldb2; kc = k0 - K1; }
        unsigned short* Asb = As + pb * (TR * 64);
        unsigned short* Bsb = Bs + pb * (TC * 64);
        #pragma unroll
        for (int i = 0; i < TR / 32; ++i) {
            int rr = w * (TR / 4) + i * 8;
            const unsigned short* ga = Ab + (tm + rr + lrow8) * la + kc + lcol_sw;
            __builtin_amdgcn_global_load_lds((gas_ptr)ga, (las_ptr)(Asb + rr * 64), 16, 0, 0);
        }
        #pragma unroll
        for (int i = 0; i < TC / 32; ++i) {
            int rr = w * (TC / 4) + i * 8;
            const unsigned short* gb = Bb + (tn + rr + lrow8) * lb + kc + lcol_sw;
            __builtin_amdgcn_global_load_lds((gas_ptr)gb, (las_ptr)(Bsb + rr * 64), 16, 0, 0);
        }
    };

    stage(0, 0);
    const int nt = K >> 6;
    for (int t = 0; t < nt; ++t) {
        const int cur = t & 1;
        if (t + 1 < nt) {
            stage((t + 1) << 6, cur ^ 1);
            waitcnt_vm<NL>();     // wait only for buf[cur]'s loads
        } else {
            waitcnt_vm<0>();
        }
        hard_barrier();
        const unsigned short* Asb = As + cur * (TR * 64);
        const unsigned short* Bsb = Bs + cur * (TC * 64);
        #pragma unroll
        for (int kk = 0; kk < 2; ++kk) {
            bf16x8 af[WM], bfr[WN];
            #pragma unroll
            for (int mi = 0; mi < WM; ++mi) {
                int r = m_off + mi * 16 + lm;
                af[mi] = *(const bf16x8*)(Asb + r * 64 + (((kk * 4 + quad) ^ (r & 7)) * 8));
            }
            #pragma unroll
            for (int ni = 0; ni < WN; ++ni) {
                int r = n_off + ni * 16 + lm;
                bfr[ni] = *(const bf16x8*)(Bsb + r * 64 + (((kk * 4 + quad) ^ (r & 7)) * 8));
            }
            #pragma unroll
            for (int mi = 0; mi < WM; ++mi)
                #pragma unroll
                for (int ni = 0; ni < WN; ++ni)
                    acc[mi][ni] = __builtin_amdgcn_mfma_f32_16x16x32_bf16(
                        af[mi], bfr[ni], acc[mi][ni], 0, 0, 0);
        }
        hard_barrier();   // all waves done reading buf[cur]
    }

    #pragma unroll
    for (int mi = 0; mi < WM; ++mi) {
        #pragma unroll
        for (int ni = 0; ni < WN; ++ni) {
            long col = tn + n_off + ni * 16 + lm;
            float bv = bias[col];
            #pragma unroll
            for (int r = 0; r < 4; ++r) {
                long row = tm + m_off + mi * 16 + quad * 4 + r;   // C/D: col=lane&15, row=quad*4+reg
                float v = acc[mi][ni][r] + bv;
                if (G1E) {
                    if (col < 768) {
                        g1_qf[row * 768 + col] = v;
                        g1_qb[row * 768 + col] = f2bf(v);
                    } else if (col < 1536) {
                        g1_kxb[row * 768 + (col - 768)] = f2bf(v);
                    } else {
                        int j = (int)col - 1536, h = j >> 6, d = j & 63;
                        int bb = (int)row >> 8, nn = (int)row & 255;
                        g1_vxT[((long)(bb * 12 + h) * 64 + d) * 256 + nn] = f2bf(v);
                    }
                } else {
                    long idx = obase + row * ldc + col;
                    if (cin) v += cin[idx];
                    if (OUT == 0) ((float*)Cout)[idx] = v;
                    else ((unsigned short*)Cout)[idx] = f2bf(v);
                }
            }
        }
    }
}

// ---------------- mega: the whole dependent chain in ONE cooperative kernel ----------------
struct MegaArgs {
    const unsigned short* xb;
    const unsigned short* w1t;
    const unsigned short* wkvb;
    const unsigned short* wpt;
    const float* bias1;
    const float* zbuf;
    const float* bkv;
    const float* bp;
    float* qf;
    unsigned short* qb;
    unsigned short* kxb;
    unsigned short* vxT;
    unsigned short* qWb;
    const unsigned short* simb;
    const float* sim;
    float* sgbuf;
    unsigned short* agb;
    float* outg0;
    unsigned short* simbar;
    unsigned short* attnb;
    float* out;
};

union GSmem {
    struct { unsigned short As[2 * 64 * 64]; unsigned short Bs[2 * 64 * 64]; } g;   // 32 KB
    struct { unsigned short qw[16 * 784]; unsigned short ss[2 * 64 * 64]; } sl;     // 41.4 KB
};

__global__ __launch_bounds__(256, 2)
void mega_kernel(MegaArgs a) {
    __shared__ GSmem sm;
    __shared__ float sclp_l[12][64];
    __shared__ float al_l[12][64];
    __shared__ float slb_l[12];
    cg::grid_group grid = cg::this_grid();
    const int bid = blockIdx.x;
    const int t = threadIdx.x;
    const int w = t >> 6, lane = t & 63;
    const int lm = lane & 15, quad = lane >> 4;

    // ---- P1: GEMM1  x @ [Wq|Wkv] + bias -> qf/qb, kxb, vxT (288 jobs, 64x64) ----
    if (bid < 288) {
        int bx = bid % 36, by = bid / 36;
        gemm_body<2, 2, 2, true>(
            a.xb, 768, a.w1t, 768, nullptr, 0, nullptr, 0, 1 << 30,
            a.bias1, nullptr, 768, 768, nullptr, 0, 0,
            (long)by * 64, (long)bx * 64, sm.g.As, sm.g.Bs,
            a.qf, a.qb, a.kxb, a.vxT);
    }
    __threadfence(); grid.sync();

    // ---- P2: qW (1152 jobs) + SG (384 jobs), 3 jobs/block ----
    for (int job = bid; job < 1536; job += 512) {
        if (job < 1152) {
            int bx = job % 12, by = (job / 12) % 8, h = job / 96;
            gemm_body<2, 2, 2, false>(
                a.qb + h * 64, 768, a.wkvb + h * 64, 1536,
                nullptr, 0, nullptr, 0, 1 << 30,
                a.zbuf, a.qWb, 768, 64, nullptr, 1, (long)h * 393216,
                (long)by * 64, (long)bx * 64, sm.g.As, sm.g.Bs,
                nullptr, nullptr, nullptr, nullptr);
        } else {
            int j2 = job - 1152;
            int bx = j2 % 4, by = (j2 / 4) % 4, z = j2 / 16;
            int zb = z / 12, zh = z % 12;
            gemm_body<2, 2, 2, false>(
                a.qb + zb * 196608 + zh * 64, 768, a.kxb + zb * 196608 + zh * 64, 768,
                nullptr, 0, nullptr, 0, 1 << 30,
                a.zbuf, a.sgbuf, 256, 64, nullptr, 0,
                (long)zb * 786432 + (long)zh * 65536,
                (long)by * 64, (long)bx * 64, sm.g.As, sm.g.Bs,
                nullptr, nullptr, nullptr, nullptr);
        }
    }
    __threadfence(); grid.sync();

    // ---- P3+P4: sl GEMM (simb bf16, dbuf+counted vmcnt) -> softmax -> simbar ----
    {
        const int n_ = bid;
        const int b = n_ >> 8, n = n_ & 255;
        const int lrow8 = lane >> 3;
        const int lcol_sw = ((lane & 7) ^ lrow8) * 8;
        const unsigned short* simn_b = a.simb + (long)n_ * 49152;   // 64 x 768 bf16
        const float* simn = a.sim + (long)n_ * 49152;               // 64 x 768 fp32

        auto stage = [&](int c, int pb) {
            unsigned short* dst = sm.sl.ss + pb * 4096;
            #pragma unroll
            for (int i = 0; i < 2; ++i) {
                int rr = w * 16 + i * 8;
                const unsigned short* ga = simn_b + (rr + lrow8) * 768 + c * 64 + lcol_sw;
                __builtin_amdgcn_global_load_lds((gas_ptr)ga, (las_ptr)(dst + rr * 64), 16, 0, 0);
            }
        };
        stage(0, 0);

        // qW staging (12 x 768 bf16) + slb via shuffle
        for (int idx = t; idx < 1152; idx += 256) {
            int h = idx / 96, c = idx - h * 96;
            *(bf16x8*)(sm.sl.qw + h * 784 + c * 8) =
                *(const bf16x8*)(a.qWb + ((long)h * 512 + n_) * 768 + c * 8);
        }
        {
            float p0 = a.qf[(long)n_ * 768 + t] * a.bkv[t];
            float p1 = a.qf[(long)n_ * 768 + t + 256] * a.bkv[t + 256];
            float p2 = a.qf[(long)n_ * 768 + t + 512] * a.bkv[t + 512];
            #pragma unroll
            for (int off = 32; off > 0; off >>= 1) {
                p0 += __shfl_xor(p0, off);
                p1 += __shfl_xor(p1, off);
                p2 += __shfl_xor(p2, off);
            }
            if (lane == 0) { slb_l[w] = p0; slb_l[w + 4] = p1; slb_l[w + 8] = p2; }
        }
        __syncthreads();

        f32x4 acc = {};
        const int r = w * 16 + lm;
        for (int c = 0; c < 12; ++c) {
            const int cur = c & 1;
            if (c + 1 < 12) {
                stage(c + 1, cur ^ 1);
                waitcnt_vm<2>();
            } else {
                waitcnt_vm<0>();
            }
            hard_barrier();
            const unsigned short* buf = sm.sl.ss + cur * 4096;
            #pragma unroll
            for (int kk = 0; kk < 2; ++kk) {
                bf16x8 af = *(const bf16x8*)(buf + r * 64 + (((kk * 4 + quad) ^ (r & 7)) * 8));
                bf16x8 bfr = *(const bf16x8*)(sm.sl.qw + lm * 784 + c * 64 + kk * 32 + quad * 8);
                acc = __builtin_amdgcn_mfma_f32_16x16x32_bf16(af, bfr, acc, 0, 0, 0);
            }
            hard_barrier();
        }
        if (lm < 12) {   // D: col=lm (head), row=quad*4+r2 (m)
            #pragma unroll
            for (int r2 = 0; r2 < 4; ++r2)
                sclp_l[lm][w * 16 + quad * 4 + r2] = acc[r2];
        }
        __syncthreads();

        // softmax: wave w handles heads 3w..3w+2
        #pragma unroll
        for (int i = 0; i < 3; ++i) {
            const int h = w * 3 + i;
            const float* sgr = a.sgbuf + (long)(b * 12 + h) * 65536 + (long)n * 256;
            float v0 = sgr[lane] * 0.125f, v1 = sgr[lane + 64] * 0.125f,
                  v2 = sgr[lane + 128] * 0.125f, v3 = sgr[lane + 192] * 0.125f;
            float v4 = (sclp_l[h][lane] + slb_l[h]) * 0.125f;
            float mx = fmaxf(fmaxf(fmaxf(v0, v1), fmaxf(v2, v3)), v4);
            #pragma unroll
            for (int off = 32; off > 0; off >>= 1) mx = fmaxf(mx, __shfl_xor(mx, off));
            float e0 = __expf(v0 - mx), e1 = __expf(v1 - mx), e2 = __expf(v2 - mx),
                  e3 = __expf(v3 - mx), e4 = __expf(v4 - mx);
            float s = e0 + e1 + e2 + e3 + e4;
            #pragma unroll
            for (int off = 32; off > 0; off >>= 1) s += __shfl_xor(s, off);
            float inv = __frcp_rn(s);
            unsigned short* agr = a.agb + (long)(b * 12 + h) * 65536 + (long)n * 256;
            agr[lane] = f2bf(e0 * inv); agr[lane + 64] = f2bf(e1 * inv);
            agr[lane + 128] = f2bf(e2 * inv); agr[lane + 192] = f2bf(e3 * inv);
            float al = e4 * inv;
            al_l[h][lane] = al;
            float am = al;
            #pragma unroll
            for (int off = 32; off > 0; off >>= 1) am += __shfl_xor(am, off);
            a.outg0[(long)n_ * 768 + h * 64 + lane] = am * a.bkv[768 + h * 64 + lane];
        }
        __syncthreads();

        // simbar: 3 col-groups of 256 (fp32 sim, L3-hot; numerics unchanged)
        #pragma unroll
        for (int cg3 = 0; cg3 < 3; ++cg3) {
            const int c = cg3 * 256 + t;
            float av[12];
            #pragma unroll
            for (int h = 0; h < 12; ++h) av[h] = 0.f;
            #pragma unroll 4
            for (int m = 0; m < 64; ++m) {
                float s = simn[(long)m * 768 + c];
                #pragma unroll
                for (int h = 0; h < 12; ++h) av[h] += al_l[h][m] * s;
            }
            #pragma unroll
            for (int h = 0; h < 12; ++h)
                a.simbar[((long)h * 512 + n_) * 768 + c] = f2bf(av[h]);
        }
    }
    __threadfence(); grid.sync();

    // ---- P5: attnb = bf16([simbar | ag] @ [WvT | vxT]^T + outg0)  (96 jobs, 64x64) ----
    if (bid < 96) {
        int by = bid % 4, z = bid / 4;
        int zb = z / 12, zh = z % 12;
        gemm_body<2, 2, 2, false>(
            a.simbar + zb * 196608L + zh * 393216L, 768,
            a.w1t + 1536L * 768 + zh * 49152L, 768,
            a.agb + zb * 786432L + zh * 65536L, 256,
            a.vxT + zb * 196608L + zh * 16384L, 256, 768,
            a.zbuf, a.attnb, 768, 1024, a.outg0, 1,
            (long)zb * 196608 + (long)zh * 64,
            (long)by * 64, 0, sm.g.As, sm.g.Bs,
            nullptr, nullptr, nullptr, nullptr);
    }
    __threadfence(); grid.sync();

    // ---- P6: out = attnb @ Wp + bp  (96 jobs, 64x64) ----
    if (bid < 96) {
        int bx = bid % 12, by = bid / 12;
        gemm_body<2, 2, 2, false>(
            a.attnb, 768, a.wpt, 768, nullptr, 0, nullptr, 0, 1 << 30,
            a.bp, a.out, 768, 768, nullptr, 0, 0,
            (long)by * 64, (long)bx * 64, sm.g.As, sm.g.Bs,
            nullptr, nullptr, nullptr, nullptr);
    }
}

// ---------------- launch ----------------

extern "C" void kernel_launch(void* const* d_in, const int* in_sizes, int n_in,
                              void* d_out, int out_size, void* d_ws, size_t ws_size,
                              hipStream_t stream) {
    const float* x   = (const float*)d_in[0];   // (2,256,768)
    const float* sim = (const float*)d_in[1];   // (2,256,64,768)
    const float* Wq  = (const float*)d_in[2];   // (768,768)
    const float* bq  = (const float*)d_in[3];   // (768)
    const float* Wkv = (const float*)d_in[4];   // (768,1536)
    const float* bkv = (const float*)d_in[5];   // (1536)
    const float* Wp  = (const float*)d_in[6];   // (768,768)
    const float* bp  = (const float*)d_in[7];   // (768)
    float* out = (float*)d_out;                 // (2,256,768) fp32

    char* ws = (char*)d_ws;
    size_t off = 0;
    auto alloc = [&](size_t bytes) {
        char* p = ws + off;
        off += (bytes + 255) & ~(size_t)255;
        return p;
    };
    unsigned short* xb     = (unsigned short*)alloc(512UL * 768 * 2);       // x bf16
    unsigned short* w1t    = (unsigned short*)alloc(2304UL * 768 * 2);      // [Wq|Wkv]^T bf16
    unsigned short* wkvb   = (unsigned short*)alloc(768UL * 1536 * 2);      // Wkv bf16
    unsigned short* wpt    = (unsigned short*)alloc(768UL * 768 * 2);       // Wp^T bf16
    float*          qf     = (float*)alloc(512UL * 768 * 4);                // q fp32
    unsigned short* qb     = (unsigned short*)alloc(512UL * 768 * 2);       // q bf16
    unsigned short* kxb    = (unsigned short*)alloc(512UL * 768 * 2);       // k_x bf16
    unsigned short* vxT    = (unsigned short*)alloc(24UL * 64 * 256 * 2);   // v_x^T per (b,h)
    unsigned short* qWb    = (unsigned short*)alloc(12UL * 512 * 768 * 2);  // qW bf16
    unsigned short* simb   = (unsigned short*)alloc(512UL * 64 * 768 * 2);  // sim bf16
    float*          sgbuf  = (float*)alloc(24UL * 65536 * 4);               // sg fp32
    unsigned short* agb    = (unsigned short*)alloc(24UL * 65536 * 2);      // ag bf16
    float*          outg0  = (float*)alloc(512UL * 768 * 4);                // alm*bkv_v fp32
    unsigned short* simbar = (unsigned short*)alloc(12UL * 512 * 768 * 2);  // simbar bf16
    unsigned short* attnb  = (unsigned short*)alloc(512UL * 768 * 2);       // attn out bf16
    float*          bias1  = (float*)alloc(2304UL * 4);                     // [bq|bkv]
    float*          zbuf   = (float*)alloc(768UL * 4);                      // zeros

    // prep: casts + bias + transposes + simcast (2124 + 12288 blocks)
    prep_all_kernel<<<14412, 256, 0, stream>>>(
        x, xb, Wkv, wkvb, bq, bkv, bias1, zbuf, Wq, Wp, w1t, wpt, sim, simb);

    // the entire dependent chain: one cooperative launch, 512 blocks (2/CU)
    MegaArgs ma;
    ma.xb = xb; ma.w1t = w1t; ma.wkvb = wkvb; ma.wpt = wpt;
    ma.bias1 = bias1; ma.zbuf = zbuf; ma.bkv = bkv; ma.bp = bp;
    ma.qf = qf; ma.qb = qb; ma.kxb = kxb; ma.vxT = vxT; ma.qWb = qWb;
    ma.simb = simb; ma.sim = sim;
    ma.sgbuf = sgbuf; ma.agb = agb; ma.outg0 = outg0;
    ma.simbar = simbar; ma.attnb = attnb; ma.out = out;
    void* kargs[] = { (void*)&ma };
    hipLaunchCooperativeKernel((void*)mega_kernel, dim3(512), dim3(256),
                               kargs, 0, stream);
}

// Round 7
// 244.624 us; speedup vs baseline: 2.8864x; 2.8864x over previous
//
#include <hip/hip_runtime.h>
#include <stdint.h>

#define DEV_INLINE __device__ __forceinline__

typedef __bf16 bf16x8 __attribute__((ext_vector_type(8)));
typedef float f32x4 __attribute__((ext_vector_type(4)));

typedef const __attribute__((address_space(1))) void* gas_ptr;
typedef __attribute__((address_space(3))) void* las_ptr;

DEV_INLINE unsigned short f2bf(float f) {
    union { __bf16 h; unsigned short u; } v;
    v.h = (__bf16)f;            // native RNE cvt
    return v.u;
}

template <int N> DEV_INLINE void waitcnt_vm() {
    asm volatile("s_waitcnt vmcnt(%0)" :: "n"(N) : "memory");
}
DEV_INLINE void hard_barrier() {
    __builtin_amdgcn_sched_barrier(0);
    __builtin_amdgcn_s_barrier();
    __builtin_amdgcn_sched_barrier(0);
}

// ------- prep: casts + bias + 3 transposes (one launch; simcast REMOVED) -------
__global__ __launch_bounds__(256)
void prep_all_kernel(const float* __restrict__ x, unsigned short* __restrict__ xb,
                     const float* __restrict__ Wkv, unsigned short* __restrict__ wkvb,
                     const float* __restrict__ bq, const float* __restrict__ bkv,
                     float* __restrict__ bias1, float* __restrict__ zbuf,
                     const float* __restrict__ Wq, const float* __restrict__ Wp,
                     unsigned short* __restrict__ w1t, unsigned short* __restrict__ wpt) {
    __shared__ float tl[64][65];
    const int bid = blockIdx.x, t = threadIdx.x;
    if (bid < 1536) {
        const float* s; unsigned short* d; long i;
        if (bid < 384) { s = x;   d = xb;   i = (long)bid * 256 + t; }
        else           { s = Wkv; d = wkvb; i = (long)(bid - 384) * 256 + t; }
        float4 a = ((const float4*)s)[i];
        ushort4 o;
        o.x = f2bf(a.x); o.y = f2bf(a.y); o.z = f2bf(a.z); o.w = f2bf(a.w);
        ((ushort4*)d)[i] = o;
    } else if (bid < 1548) {
        int i = (bid - 1536) * 256 + t;   // [0,3072)
        if (i < 768) bias1[i] = bq[i];
        else if (i < 2304) bias1[i] = bkv[i - 768];
        else zbuf[i - 2304] = 0.f;
    } else {
        int tb = bid - 1548;              // [0,576)
        int bx = tb % 48, by = tb / 48;
        const float* src; unsigned short* dst; int C;
        if (bx < 12)      { src = Wq;  dst = w1t;              C = 768; }
        else if (bx < 36) { src = Wkv; dst = w1t + 768L * 768; C = 1536; bx -= 12; }
        else              { src = Wp;  dst = wpt;              C = 768; bx -= 36; }
        int c0 = bx * 64, r0 = by * 64;
        int tx = t & 63, ty = t >> 6;     // 64 x 4
        #pragma unroll
        for (int i = 0; i < 64; i += 4)
            tl[ty + i][tx] = src[(long)(r0 + ty + i) * C + c0 + tx];
        __syncthreads();
        #pragma unroll
        for (int i = 0; i < 64; i += 4)
            dst[(long)(c0 + ty + i) * 768 + r0 + tx] = f2bf(tl[tx][ty + i]);
    }
}

// ---------------- unified bf16 MFMA GEMM body (2-phase pipelined) ----------------
template <int WM, int WN, int WAVES_M, bool G1E>
DEV_INLINE void gemm_body(const unsigned short* A, int lda,
                          const unsigned short* BT, int ldb,
                          const unsigned short* A2, int lda2,
                          const unsigned short* B2, int ldb2, int K1,
                          const float* bias, void* Cout, int ldc, int K,
                          const float* cin, int OUT, long obase, long tm, long tn,
                          unsigned short* As, unsigned short* Bs,
                          float* g1_qf, unsigned short* g1_qb,
                          unsigned short* g1_kxb, unsigned short* g1_vxT) {
    constexpr int TR = WAVES_M * WM * 16;
    constexpr int TC = (4 / WAVES_M) * WN * 16;
    constexpr int NL = TR / 32 + TC / 32;   // global_load_lds per wave per stage
    const int tid = threadIdx.x;
    const int w = tid >> 6, lane = tid & 63;
    const int lm = lane & 15, quad = lane >> 4;
    const int m_off = (w % WAVES_M) * WM * 16;
    const int n_off = (w / WAVES_M) * WN * 16;
    const int lrow8 = lane >> 3;
    const int lcol_sw = (((lane & 7) ^ lrow8) * 8);

    f32x4 acc[WM][WN];
    #pragma unroll
    for (int mi = 0; mi < WM; ++mi)
        #pragma unroll
        for (int ni = 0; ni < WN; ++ni) acc[mi][ni] = f32x4{0.f, 0.f, 0.f, 0.f};

    auto stage = [&](int k0, int pb) {
        const unsigned short* Ab; const unsigned short* Bb;
        int la, lb, kc;
        if (k0 < K1) { Ab = A;  Bb = BT; la = lda;  lb = ldb;  kc = k0; }
        else         { Ab = A2; Bb = B2; la = lda2; lb = ldb2; kc = k0 - K1; }
        unsigned short* Asb = As + pb * (TR * 64);
        unsigned short* Bsb = Bs + pb * (TC * 64);
        #pragma unroll
        for (int i = 0; i < TR / 32; ++i) {
            int rr = w * (TR / 4) + i * 8;
            const unsigned short* ga = Ab + (tm + rr + lrow8) * la + kc + lcol_sw;
            __builtin_amdgcn_global_load_lds((gas_ptr)ga, (las_ptr)(Asb + rr * 64), 16, 0, 0);
        }
        #pragma unroll
        for (int i = 0; i < TC / 32; ++i) {
            int rr = w * (TC / 4) + i * 8;
            const unsigned short* gb = Bb + (tn + rr + lrow8) * lb + kc + lcol_sw;
            __builtin_amdgcn_global_load_lds((gas_ptr)gb, (las_ptr)(Bsb + rr * 64), 16, 0, 0);
        }
    };

    stage(0, 0);
    const int nt = K >> 6;
    for (int t = 0; t < nt; ++t) {
        const int cur = t & 1;
        if (t + 1 < nt) {
            stage((t + 1) << 6, cur ^ 1);
            waitcnt_vm<NL>();     // wait only for buf[cur]'s loads
        } else {
            waitcnt_vm<0>();
        }
        hard_barrier();
        const unsigned short* Asb = As + cur * (TR * 64);
        const unsigned short* Bsb = Bs + cur * (TC * 64);
        #pragma unroll
        for (int kk = 0; kk < 2; ++kk) {
            bf16x8 af[WM], bfr[WN];
            #pragma unroll
            for (int mi = 0; mi < WM; ++mi) {
                int r = m_off + mi * 16 + lm;
                af[mi] = *(const bf16x8*)(Asb + r * 64 + (((kk * 4 + quad) ^ (r & 7)) * 8));
            }
            #pragma unroll
            for (int ni = 0; ni < WN; ++ni) {
                int r = n_off + ni * 16 + lm;
                bfr[ni] = *(const bf16x8*)(Bsb + r * 64 + (((kk * 4 + quad) ^ (r & 7)) * 8));
            }
            #pragma unroll
            for (int mi = 0; mi < WM; ++mi)
                #pragma unroll
                for (int ni = 0; ni < WN; ++ni)
                    acc[mi][ni] = __builtin_amdgcn_mfma_f32_16x16x32_bf16(
                        af[mi], bfr[ni], acc[mi][ni], 0, 0, 0);
        }
        hard_barrier();   // all waves done reading buf[cur]
    }

    #pragma unroll
    for (int mi = 0; mi < WM; ++mi) {
        #pragma unroll
        for (int ni = 0; ni < WN; ++ni) {
            long col = tn + n_off + ni * 16 + lm;
            float bv = bias[col];
            #pragma unroll
            for (int r = 0; r < 4; ++r) {
                long row = tm + m_off + mi * 16 + quad * 4 + r;   // C/D: col=lane&15, row=quad*4+reg
                float v = acc[mi][ni][r] + bv;
                if (G1E) {
                    if (col < 768) {
                        g1_qf[row * 768 + col] = v;
                        g1_qb[row * 768 + col] = f2bf(v);
                    } else if (col < 1536) {
                        g1_kxb[row * 768 + (col - 768)] = f2bf(v);
                    } else {
                        int j = (int)col - 1536, h = j >> 6, d = j & 63;
                        int bb = (int)row >> 8, nn = (int)row & 255;
                        g1_vxT[((long)(bb * 12 + h) * 64 + d) * 256 + nn] = f2bf(v);
                    }
                } else {
                    long idx = obase + row * ldc + col;
                    if (cin) v += cin[idx];
                    if (OUT == 0) ((float*)Cout)[idx] = v;
                    else ((unsigned short*)Cout)[idx] = f2bf(v);
                }
            }
        }
    }
}

// standard wrapper: batch z -> zb=z/12, zh=z%12
template <int WM, int WN, int WAVES_M, bool G1E>
__global__ __launch_bounds__(256)
void gemm_bf16_kernel(const unsigned short* __restrict__ A, int lda,
                      const unsigned short* __restrict__ BT, int ldb,
                      const float* __restrict__ bias,
                      void* __restrict__ Cout, int ldc, int K,
                      const float* __restrict__ cin, int OUT,
                      long aZb, long aZh, long bZb, long bZh, long oZb, long oZh,
                      float* __restrict__ g1_qf, unsigned short* __restrict__ g1_qb,
                      unsigned short* __restrict__ g1_kxb,
                      unsigned short* __restrict__ g1_vxT) {
    constexpr int TR = WAVES_M * WM * 16;
    constexpr int TC = (4 / WAVES_M) * WN * 16;
    __shared__ unsigned short As[2 * TR * 64];
    __shared__ unsigned short Bs[2 * TC * 64];
    const int z = blockIdx.z, zb = z / 12, zh = z % 12;
    gemm_body<WM, WN, WAVES_M, G1E>(
        A + zb * aZb + zh * aZh, lda, BT + zb * bZb + zh * bZh, ldb,
        nullptr, 0, nullptr, 0, 1 << 30,
        bias, Cout, ldc, K, cin, OUT, zb * oZb + zh * oZh,
        (long)blockIdx.y * TR, (long)blockIdx.x * TC, As, Bs,
        g1_qf, g1_qb, g1_kxb, g1_vxT);
}

// fused qW + SG launch: 1D grid of 1152 + 384
__global__ __launch_bounds__(256)
void gemm_qwsg_kernel(const unsigned short* __restrict__ qb,
                      const unsigned short* __restrict__ wkvb,
                      const unsigned short* __restrict__ kxb,
                      const float* __restrict__ zbuf,
                      unsigned short* __restrict__ qWb,
                      float* __restrict__ sgbuf) {
    __shared__ unsigned short As[2 * 64 * 64];
    __shared__ unsigned short Bs[2 * 64 * 64];
    int bid = blockIdx.x;
    if (bid < 1152) {
        // qW: qW_h = q_h @ Wk_h^T  (512x768, K=64), bf16 out
        int bx = bid % 12, by = (bid / 12) % 8, h = bid / 96;
        gemm_body<2, 2, 2, false>(
            qb + h * 64, 768, wkvb + h * 64, 1536,
            nullptr, 0, nullptr, 0, 1 << 30,
            zbuf, qWb, 768, 64, nullptr, 1, (long)h * 393216,
            (long)by * 64, (long)bx * 64, As, Bs,
            nullptr, nullptr, nullptr, nullptr);
    } else {
        // SG: sg = q_h @ k_x,h^T per (b,h)  (256x256, K=64), fp32 out
        int bid2 = bid - 1152;
        int bx = bid2 % 4, by = (bid2 / 4) % 4, z = bid2 / 16;
        int zb = z / 12, zh = z % 12;
        gemm_body<2, 2, 2, false>(
            qb + zb * 196608 + zh * 64, 768, kxb + zb * 196608 + zh * 64, 768,
            nullptr, 0, nullptr, 0, 1 << 30,
            zbuf, sgbuf, 256, 64, nullptr, 0,
            (long)zb * 786432 + (long)zh * 65536,
            (long)by * 64, (long)bx * 64, As, Bs,
            nullptr, nullptr, nullptr, nullptr);
    }
}

// concat-K wrapper: attnb = bf16([simbar | ag] @ [WvT | vxT]^T + outg0)
template <int WM, int WN, int WAVES_M>
__global__ __launch_bounds__(256)
void gemm_concat_kernel(const unsigned short* __restrict__ A, int lda, long aZb, long aZh,
                        const unsigned short* __restrict__ BT, int ldb, long bZb, long bZh,
                        const unsigned short* __restrict__ A2, int lda2, long a2Zb, long a2Zh,
                        const unsigned short* __restrict__ B2, int ldb2, long b2Zb, long b2Zh,
                        int K1, int K, const float* __restrict__ bias,
                        void* __restrict__ Cout, int ldc,
                        const float* __restrict__ cin, int OUT, long oZb, long oZh) {
    constexpr int TR = WAVES_M * WM * 16;
    constexpr int TC = (4 / WAVES_M) * WN * 16;
    __shared__ unsigned short As[2 * TR * 64];
    __shared__ unsigned short Bs[2 * TC * 64];
    const int z = blockIdx.z, zb = z / 12, zh = z % 12;
    gemm_body<WM, WN, WAVES_M, false>(
        A + zb * aZb + zh * aZh, lda, BT + zb * bZb + zh * bZh, ldb,
        A2 + zb * a2Zb + zh * a2Zh, lda2, B2 + zb * b2Zb + zh * b2Zh, ldb2, K1,
        bias, Cout, ldc, K, cin, OUT, zb * oZb + zh * oZh,
        (long)blockIdx.y * TR, (long)blockIdx.x * TC, As, Bs,
        nullptr, nullptr, nullptr, nullptr);
}

// ---------------- sl partials: one block per (n_, k-chunk) -- 6144 independent blocks ----
// sclp[c][n_][h][m] = sum_{d in chunk c} sim[n_][m][d] * qW[n_][h][d]  (fp32 partial)
// Fill-kernel-shaped: 10 KB LDS, 1 barrier, no chunk serialization -> deep cross-block
// load overlap (~24 blocks/CU queued) -> sim streams at HBM rate.
__global__ __launch_bounds__(256)
void slpart3_kernel(const float* __restrict__ sim,
                    const unsigned short* __restrict__ qWb,
                    float* __restrict__ sclp) {
    __shared__ unsigned short ss[64 * 64];    // 8 KB, XOR-swizzled
    __shared__ unsigned short qwc[16 * 64];   // 2 KB, rows 12-15 zeroed
    const int t = threadIdx.x;
    const int lane = t & 63, w = t >> 6;
    const int lm = lane & 15, quad = lane >> 4;
    const int n_ = blockIdx.x, c = blockIdx.y;
    const float* simn = sim + (long)n_ * 49152 + c * 64;

    // stage sim chunk: thread t -> row r=t>>2, 16 fp32 cols at q*16 (64 B contiguous)
    {
        int r = t >> 2, q = t & 3;
        const float* gp = simn + (long)r * 768 + q * 16;
        float4 a0 = *(const float4*)gp;
        float4 a1 = *(const float4*)(gp + 4);
        float4 a2 = *(const float4*)(gp + 8);
        float4 a3 = *(const float4*)(gp + 12);
        union { bf16x8 v; unsigned short u[8]; } p;
        p.u[0] = f2bf(a0.x); p.u[1] = f2bf(a0.y); p.u[2] = f2bf(a0.z); p.u[3] = f2bf(a0.w);
        p.u[4] = f2bf(a1.x); p.u[5] = f2bf(a1.y); p.u[6] = f2bf(a1.z); p.u[7] = f2bf(a1.w);
        *(bf16x8*)(ss + r * 64 + (((q * 2) ^ (r & 7)) * 8)) = p.v;
        p.u[0] = f2bf(a2.x); p.u[1] = f2bf(a2.y); p.u[2] = f2bf(a2.z); p.u[3] = f2bf(a2.w);
        p.u[4] = f2bf(a3.x); p.u[5] = f2bf(a3.y); p.u[6] = f2bf(a3.z); p.u[7] = f2bf(a3.w);
        *(bf16x8*)(ss + r * 64 + (((q * 2 + 1) ^ (r & 7)) * 8)) = p.v;
    }
    if (t < 96) {          // qW chunk: h = t>>3, 8 bf16 at j*8
        int h = t >> 3, j = t & 7;
        *(bf16x8*)(qwc + h * 64 + j * 8) =
            *(const bf16x8*)(qWb + ((long)h * 512 + n_) * 768 + c * 64 + j * 8);
    } else if (t < 128) {  // zero junk rows 12-15 (keeps MFMA inputs finite)
        *(bf16x8*)(qwc + 12 * 64 + (t - 96) * 8) = bf16x8{};
    }
    __syncthreads();

    // MFMA: wave w -> m-tile w (rows w*16..w*16+15), K=64 (2 k-steps)
    f32x4 acc = {};
    const int r = w * 16 + lm;
    #pragma unroll
    for (int kk = 0; kk < 2; ++kk) {
        bf16x8 af = *(const bf16x8*)(ss + r * 64 + (((kk * 4 + quad) ^ (r & 7)) * 8));
        bf16x8 bf_ = *(const bf16x8*)(qwc + lm * 64 + kk * 32 + quad * 8);
        acc = __builtin_amdgcn_mfma_f32_16x16x32_bf16(af, bf_, acc, 0, 0, 0);
    }
    if (lm < 12) {   // D: col=lm (head), row=quad*4+r2 (m)
        float* dst = sclp + (((long)c * 512 + n_) * 12 + lm) * 64 + w * 16 + quad * 4;
        #pragma unroll
        for (int r2 = 0; r2 < 4; ++r2) dst[r2] = acc[r2];
    }
}

// ---------------- softmax + simbar (wide grid, sim fp32 L3-hot) ----------------
// Block (n_, cg): softmax over [sg(256)|sl(64)] per head (sl = sum of 12 k-chunk
// partials, ascending -- order matches previous MFMA accumulation); only cg==0
// writes agb/outg0; simbar cols [cg*256, cg*256+256).
__global__ __launch_bounds__(256)
void attn2_kernel(const float* __restrict__ sim,
                  const float* __restrict__ qf,
                  const float* __restrict__ bkv,
                  const float* __restrict__ sclp,
                  const float* __restrict__ sgbuf,
                  unsigned short* __restrict__ agb,
                  float* __restrict__ outg0,
                  unsigned short* __restrict__ simbar) {
    __shared__ float slb_s[12];
    __shared__ float al_s[12][64];
    const int t = threadIdx.x;
    const int lane = t & 63, w = t >> 6;
    const int n_ = blockIdx.x, cg = blockIdx.y;
    const int b = n_ >> 8, n = n_ & 255;
    const float* simn = sim + (long)n_ * 49152;

    // slb[h] = q[h] . bkv_k[h]; wave w reduces heads w, w+4, w+8 (d = lane)
    {
        float p0 = qf[(long)n_ * 768 + t] * bkv[t];
        float p1 = qf[(long)n_ * 768 + t + 256] * bkv[t + 256];
        float p2 = qf[(long)n_ * 768 + t + 512] * bkv[t + 512];
        #pragma unroll
        for (int off = 32; off > 0; off >>= 1) {
            p0 += __shfl_xor(p0, off);
            p1 += __shfl_xor(p1, off);
            p2 += __shfl_xor(p2, off);
        }
        if (lane == 0) { slb_s[w] = p0; slb_s[w + 4] = p1; slb_s[w + 8] = p2; }
    }
    __syncthreads();

    // softmax: wave w handles heads 3w..3w+2; 5 scores per lane
    #pragma unroll
    for (int i = 0; i < 3; ++i) {
        const int h = w * 3 + i;
        const float* sgr = sgbuf + (long)(b * 12 + h) * 65536 + (long)n * 256;
        float v0 = sgr[lane] * 0.125f, v1 = sgr[lane + 64] * 0.125f,
              v2 = sgr[lane + 128] * 0.125f, v3 = sgr[lane + 192] * 0.125f;
        float sp = 0.f;
        #pragma unroll
        for (int cc = 0; cc < 12; ++cc)
            sp += sclp[(((long)cc * 512 + n_) * 12 + h) * 64 + lane];
        float v4 = (sp + slb_s[h]) * 0.125f;
        float mx = fmaxf(fmaxf(fmaxf(v0, v1), fmaxf(v2, v3)), v4);
        #pragma unroll
        for (int off = 32; off > 0; off >>= 1) mx = fmaxf(mx, __shfl_xor(mx, off));
        float e0 = __expf(v0 - mx), e1 = __expf(v1 - mx), e2 = __expf(v2 - mx),
              e3 = __expf(v3 - mx), e4 = __expf(v4 - mx);
        float s = e0 + e1 + e2 + e3 + e4;
        #pragma unroll
        for (int off = 32; off > 0; off >>= 1) s += __shfl_xor(s, off);
        float inv = __frcp_rn(s);
        float al = e4 * inv;
        al_s[h][lane] = al;
        if (cg == 0) {   // block-uniform branch
            unsigned short* agr = agb + (long)(b * 12 + h) * 65536 + (long)n * 256;
            agr[lane] = f2bf(e0 * inv); agr[lane + 64] = f2bf(e1 * inv);
            agr[lane + 128] = f2bf(e2 * inv); agr[lane + 192] = f2bf(e3 * inv);
            float am = al;
            #pragma unroll
            for (int off = 32; off > 0; off >>= 1) am += __shfl_xor(am, off);
            outg0[(long)n_ * 768 + h * 64 + lane] = am * bkv[768 + h * 64 + lane];
        }
    }
    __syncthreads();

    // simbar third: col c = cg*256 + t (fp32 sim, L3-hot; precision unchanged)
    const int c = cg * 256 + t;
    float a[12];
    #pragma unroll
    for (int h = 0; h < 12; ++h) a[h] = 0.f;
    #pragma unroll 4
    for (int m = 0; m < 64; ++m) {
        float s = simn[(long)m * 768 + c];
        #pragma unroll
        for (int h = 0; h < 12; ++h) a[h] += al_s[h][m] * s;
    }
    #pragma unroll
    for (int h = 0; h < 12; ++h)
        simbar[((long)h * 512 + n_) * 768 + c] = f2bf(a[h]);
}

// ---------------- launch ----------------

extern "C" void kernel_launch(void* const* d_in, const int* in_sizes, int n_in,
                              void* d_out, int out_size, void* d_ws, size_t ws_size,
                              hipStream_t stream) {
    const float* x   = (const float*)d_in[0];   // (2,256,768)
    const float* sim = (const float*)d_in[1];   // (2,256,64,768)
    const float* Wq  = (const float*)d_in[2];   // (768,768)
    const float* bq  = (const float*)d_in[3];   // (768)
    const float* Wkv = (const float*)d_in[4];   // (768,1536)
    const float* bkv = (const float*)d_in[5];   // (1536)
    const float* Wp  = (const float*)d_in[6];   // (768,768)
    const float* bp  = (const float*)d_in[7];   // (768)
    float* out = (float*)d_out;                 // (2,256,768) fp32

    char* ws = (char*)d_ws;
    size_t off = 0;
    auto alloc = [&](size_t bytes) {
        char* p = ws + off;
        off += (bytes + 255) & ~(size_t)255;
        return p;
    };
    unsigned short* xb     = (unsigned short*)alloc(512UL * 768 * 2);       // x bf16
    unsigned short* w1t    = (unsigned short*)alloc(2304UL * 768 * 2);      // [Wq|Wkv]^T bf16
    unsigned short* wkvb   = (unsigned short*)alloc(768UL * 1536 * 2);      // Wkv bf16
    unsigned short* wpt    = (unsigned short*)alloc(768UL * 768 * 2);       // Wp^T bf16
    float*          qf     = (float*)alloc(512UL * 768 * 4);                // q fp32
    unsigned short* qb     = (unsigned short*)alloc(512UL * 768 * 2);       // q bf16
    unsigned short* kxb    = (unsigned short*)alloc(512UL * 768 * 2);       // k_x bf16
    unsigned short* vxT    = (unsigned short*)alloc(24UL * 64 * 256 * 2);   // v_x^T per (b,h)
    unsigned short* qWb    = (unsigned short*)alloc(12UL * 512 * 768 * 2);  // qW bf16
    float*          sgbuf  = (float*)alloc(24UL * 65536 * 4);               // sg fp32
    unsigned short* agb    = (unsigned short*)alloc(24UL * 65536 * 2);      // ag bf16
    float*          outg0  = (float*)alloc(512UL * 768 * 4);                // alm*bkv_v fp32
    float*          sclp   = (float*)alloc(12UL * 512 * 12 * 64 * 4);       // sl k-partials fp32
    unsigned short* simbar = (unsigned short*)alloc(12UL * 512 * 768 * 2);  // simbar bf16
    unsigned short* attnb  = (unsigned short*)alloc(512UL * 768 * 2);       // attn out bf16
    float*          bias1  = (float*)alloc(2304UL * 4);                     // [bq|bkv]
    float*          zbuf   = (float*)alloc(768UL * 4);                      // zeros

    // prep: casts + bias + transposes (2124 blocks; simcast removed)
    prep_all_kernel<<<2124, 256, 0, stream>>>(
        x, xb, Wkv, wkvb, bq, bkv, bias1, zbuf, Wq, Wp, w1t, wpt);

    // GEMM1: x @ [Wq|Wkv] + bias -> qf/qb, kxb, vxT   (512 x 2304, K=768), 32x64 tiles
    gemm_bf16_kernel<1, 2, 2, true><<<dim3(36, 16, 1), 256, 0, stream>>>(
        xb, 768, w1t, 768, bias1, nullptr, 768, 768, nullptr, 0,
        0, 0, 0, 0, 0, 0, qf, qb, kxb, vxT);

    // qW (512x768 K=64 per head) + SG (256x256 K=64 per (b,h)) fused: 1536 blocks
    gemm_qwsg_kernel<<<1536, 256, 0, stream>>>(qb, wkvb, kxb, zbuf, qWb, sgbuf);

    // sl partials: 6144 independent blocks, sim fp32 streamed once at HBM rate
    slpart3_kernel<<<dim3(512, 12), 256, 0, stream>>>(sim, qWb, sclp);

    // softmax (+12-partial sum) + simbar: 1536 blocks, sim re-read L3-hot
    attn2_kernel<<<dim3(512, 3), 256, 0, stream>>>(
        sim, qf, bkv, sclp, sgbuf, agb, outg0, simbar);

    // attnb = bf16([simbar | ag] @ [WvT | vxT]^T + outg0), per (b,h), K=768+256
    gemm_concat_kernel<1, 1, 2><<<dim3(2, 8, 24), 256, 0, stream>>>(
        simbar, 768, 196608, 393216,
        w1t + 1536L * 768, 768, 0, 49152,
        agb, 256, 786432, 65536,
        vxT, 256, 196608, 16384,
        768, 1024, zbuf, attnb, 768, outg0, 1, 196608, 64);

    // GEMM3: out = attnb @ Wp + bp   (512x768, K=768), 32x32 tiles -> 384 blocks
    gemm_bf16_kernel<1, 1, 2, false><<<dim3(24, 16, 1), 256, 0, stream>>>(
        attnb, 768, wpt, 768, bp, out, 768, 768, nullptr, 0,
        0, 0, 0, 0, 0, 0, nullptr, nullptr, nullptr, nullptr);
}